// Round 1
// baseline (941.646 us; speedup 1.0000x reference)
//
#include <hip/hip_runtime.h>
#include <hip/hip_fp16.h>

// ---------------------------------------------------------------------------
// CustomAttentionLayer: B=2, S=4096, H=2048, num_heads=16 (scale only).
// Pipeline (all on `stream`):
//   prep:      WqR = scale * Rot(wq) (fp16), WkR = Rot(wk), Wvh/Woh fp16,
//              Xh = fp16(hidden)
//   gemm_bt:   Q  = Xh·WqR^T            (8192x2048, K=2048)
//              K  = Xh·WkR^T            (8192x2048, K=2048)
//              Vt_b = Wvh·Xh_b^T        (2048x4096 per batch)  [V transposed]
//              S_b  = Q_b·K_b^T         (4096x4096 per batch)
//   softmax:   rowwise in-place on S (fp16)
//   gemm_bt:   AO_b = P_b·Vt_b^T        (4096x2048 per batch)
//              out  = AO·Woh^T  (fp32)  (8192x2048)
// Workspace: 224 MiB fp16 (AO aliases Xh — Xh dead after Vt projections).
// ---------------------------------------------------------------------------

typedef _Float16 half8 __attribute__((ext_vector_type(8)));
typedef _Float16 half4v __attribute__((ext_vector_type(4)));
typedef float f32x4 __attribute__((ext_vector_type(4)));

using gas_t = const __attribute__((address_space(1))) void;
using las_t = __attribute__((address_space(3))) void;
#define GL2LDS16(g, l) __builtin_amdgcn_global_load_lds((gas_t*)(g), (las_t*)(l), 16, 0, 0)

// ---------------------------------------------------------------------------
// C = A · B^T.  A: M x K row-major (lda), B: N x K row-major (ldb),
// C: M x N row-major (ldc).  M = gridDim.y*128, N = gridDim.x*128.
// 128x128 tile, BK=64, 4 waves (2x2), 16x16x32 f16 MFMA, fp32 accum.
// m97 structure: global_load_lds width-16 staging, 2 barriers per K-step.
// ---------------------------------------------------------------------------
template <typename OutT>
__global__ __launch_bounds__(256) void gemm_bt(
    const _Float16* __restrict__ A, const _Float16* __restrict__ B,
    OutT* __restrict__ C, int K, int lda, int ldb, int ldc) {
  __shared__ __align__(16) _Float16 As[128 * 64];
  __shared__ __align__(16) _Float16 Bs[128 * 64];

  const int tid  = threadIdx.x;
  const int lane = tid & 63;
  const int wave = tid >> 6;
  const int wr = wave >> 1, wc = wave & 1;   // wave -> 64x64 quadrant
  const int r16 = lane & 15;                 // fragment row (A) / col (B)
  const int kq  = lane >> 4;                 // k-quarter 0..3
  const size_t mBase = (size_t)blockIdx.y * 128;
  const size_t nBase = (size_t)blockIdx.x * 128;

  const int srow = lane >> 3;        // staging: row within 8-row chunk
  const int scol = (lane & 7) * 8;   // staging: halves offset within row

  f32x4 acc[4][4] = {};

  for (int kt = 0; kt < K; kt += 64) {
    __syncthreads();  // previous tile fully consumed
#pragma unroll
    for (int i = 0; i < 4; ++i) {
      const int c = wave * 4 + i;  // chunk 0..15, 8 rows each
      const _Float16* ga = A + (mBase + c * 8 + srow) * (size_t)lda + kt + scol;
      GL2LDS16(ga, &As[c * 512 + lane * 8]);
      const _Float16* gb = B + (nBase + c * 8 + srow) * (size_t)ldb + kt + scol;
      GL2LDS16(gb, &Bs[c * 512 + lane * 8]);
    }
    __syncthreads();  // staging visible (vmcnt drained at barrier)
#pragma unroll
    for (int ks = 0; ks < 2; ++ks) {
      half8 af[4], bf[4];
#pragma unroll
      for (int mf = 0; mf < 4; ++mf)
        af[mf] = *(const half8*)&As[(wr * 64 + mf * 16 + r16) * 64 + ks * 32 + kq * 8];
#pragma unroll
      for (int nf = 0; nf < 4; ++nf)
        bf[nf] = *(const half8*)&Bs[(wc * 64 + nf * 16 + r16) * 64 + ks * 32 + kq * 8];
#pragma unroll
      for (int mf = 0; mf < 4; ++mf)
#pragma unroll
        for (int nf = 0; nf < 4; ++nf)
          acc[mf][nf] = __builtin_amdgcn_mfma_f32_16x16x32_f16(af[mf], bf[nf], acc[mf][nf], 0, 0, 0);
    }
  }

  // C/D layout: col = lane&15, row = (lane>>4)*4 + reg  (verified m89/m121-128)
  const size_t crow0 = mBase + wr * 64 + kq * 4;
  const size_t ccol0 = nBase + wc * 64 + r16;
#pragma unroll
  for (int mf = 0; mf < 4; ++mf)
#pragma unroll
    for (int nf = 0; nf < 4; ++nf)
#pragma unroll
      for (int r = 0; r < 4; ++r)
        C[(crow0 + mf * 16 + r) * (size_t)ldc + ccol0 + nf * 16] = (OutT)acc[mf][nf][r];
}

// ---------------------------------------------------------------------------
// prep: z=0 rotate+scale wq -> WqR, z=1 rotate wk -> WkR,
//       z=2 wv->fp16, z=3 wo->fp16, z=4 hidden->fp16.
// Rotary (position-independent!): out[2i] = cos(a_i)*w[i] - sin(a_i)*w[i+1024]
//                                 out[2i+1]= sin(a_i)*w[i] + cos(a_i)*w[i+1024]
// ---------------------------------------------------------------------------
__global__ __launch_bounds__(256) void prep(
    const float* __restrict__ hid, const float* __restrict__ ang,
    const float* __restrict__ wq, const float* __restrict__ wk,
    const float* __restrict__ wv, const float* __restrict__ wo,
    _Float16* __restrict__ Xh, _Float16* __restrict__ WqR,
    _Float16* __restrict__ WkR, _Float16* __restrict__ Wvh,
    _Float16* __restrict__ Woh) {
  const int z = blockIdx.z;
  const int start = blockIdx.x * 256 + threadIdx.x;
  const int stride = gridDim.x * 256;
  if (z <= 1) {
    const float* w = z ? wk : wq;
    _Float16* o = z ? WkR : WqR;
    const float sc = z ? 1.0f : 0.08838834764831845f;  // 1/sqrt(2048/16)
    for (int u = start; u < 1024 * 512; u += stride) {
      const int i = u >> 9;
      const int c = (u & 511) << 2;
      const float a = ang[i];
      const float cv = cosf(a) * sc, sv = sinf(a) * sc;
      f32x4 ar = *(const f32x4*)&w[(size_t)i * 2048 + c];
      f32x4 br = *(const f32x4*)&w[(size_t)(i + 1024) * 2048 + c];
      half4v r0, r1;
#pragma unroll
      for (int j = 0; j < 4; ++j) {
        r0[j] = (_Float16)(ar[j] * cv - br[j] * sv);
        r1[j] = (_Float16)(ar[j] * sv + br[j] * cv);
      }
      *(half4v*)&o[(size_t)(2 * i) * 2048 + c] = r0;
      *(half4v*)&o[(size_t)(2 * i + 1) * 2048 + c] = r1;
    }
  } else if (z <= 3) {
    const float* w = (z == 2) ? wv : wo;
    _Float16* o = (z == 2) ? Wvh : Woh;
    for (int u = start; u < 2048 * 512; u += stride) {
      const int c = u << 2;
      f32x4 a = *(const f32x4*)&w[c];
      half4v r;
#pragma unroll
      for (int j = 0; j < 4; ++j) r[j] = (_Float16)a[j];
      *(half4v*)&o[c] = r;
    }
  } else {
    for (int u = start; u < (2 * 4096 * 2048) / 4; u += stride) {
      const int c = u << 2;
      f32x4 a = *(const f32x4*)&hid[c];
      half4v r;
#pragma unroll
      for (int j = 0; j < 4; ++j) r[j] = (_Float16)a[j];
      *(half4v*)&Xh[c] = r;
    }
  }
}

// ---------------------------------------------------------------------------
// Row-wise softmax, in place, fp16 rows of length 4096. One block per row.
// ---------------------------------------------------------------------------
__global__ __launch_bounds__(256) void softmax_rows(_Float16* __restrict__ Sm) {
  _Float16* p = Sm + (size_t)blockIdx.x * 4096;
  const int tid = threadIdx.x;
  const int lane = tid & 63, wave = tid >> 6;
  __shared__ float red[8];

  half8 v0 = *(const half8*)&p[tid * 16];
  half8 v1 = *(const half8*)&p[tid * 16 + 8];
  float x[16];
#pragma unroll
  for (int j = 0; j < 8; ++j) { x[j] = (float)v0[j]; x[8 + j] = (float)v1[j]; }

  float m = x[0];
#pragma unroll
  for (int j = 1; j < 16; ++j) m = fmaxf(m, x[j]);
#pragma unroll
  for (int msk = 32; msk >= 1; msk >>= 1) m = fmaxf(m, __shfl_xor(m, msk));
  if (lane == 0) red[wave] = m;
  __syncthreads();
  m = fmaxf(fmaxf(red[0], red[1]), fmaxf(red[2], red[3]));

  float s = 0.f;
#pragma unroll
  for (int j = 0; j < 16; ++j) { x[j] = __expf(x[j] - m); s += x[j]; }
#pragma unroll
  for (int msk = 32; msk >= 1; msk >>= 1) s += __shfl_xor(s, msk);
  if (lane == 0) red[4 + wave] = s;
  __syncthreads();
  s = red[4] + red[5] + red[6] + red[7];
  const float inv = 1.0f / s;

#pragma unroll
  for (int j = 0; j < 8; ++j) {
    v0[j] = (_Float16)(x[j] * inv);
    v1[j] = (_Float16)(x[8 + j] * inv);
  }
  *(half8*)&p[tid * 16] = v0;
  *(half8*)&p[tid * 16 + 8] = v1;
}

// ---------------------------------------------------------------------------
extern "C" void kernel_launch(void* const* d_in, const int* in_sizes, int n_in,
                              void* d_out, int out_size, void* d_ws, size_t ws_size,
                              hipStream_t stream) {
  (void)in_sizes; (void)n_in; (void)out_size; (void)ws_size;
  const float* hid = (const float*)d_in[0];
  const float* ang = (const float*)d_in[1];
  const float* wq  = (const float*)d_in[2];
  const float* wk  = (const float*)d_in[3];
  const float* wv  = (const float*)d_in[4];
  const float* wo  = (const float*)d_in[5];
  float* out = (float*)d_out;

  _Float16* ws = (_Float16*)d_ws;
  const size_t EX = 2ull * 4096 * 2048;  // 16777216 elems (32 MiB fp16)
  const size_t EH = 2048ull * 2048;      // 4194304 elems (8 MiB fp16)
  _Float16* Xh  = ws;                 // [8192][2048]
  _Float16* AO  = ws;                 // alias: Xh dead after Vt projections
  _Float16* Q   = ws + EX;            // [8192][2048]
  _Float16* Kh  = ws + 2 * EX;        // [8192][2048]
  _Float16* Vt  = ws + 3 * EX;        // per batch [2048][4096]
  _Float16* WqR = ws + 4 * EX;
  _Float16* WkR = WqR + EH;
  _Float16* Wvh = WkR + EH;
  _Float16* Woh = Wvh + EH;
  _Float16* Sm  = Woh + EH;           // [2][4096][4096] scores/probs

  prep<<<dim3(2048, 1, 5), 256, 0, stream>>>(hid, ang, wq, wk, wv, wo, Xh, WqR, WkR, Wvh, Woh);

  // Q / K projections (rotation+scale folded into weights)
  gemm_bt<_Float16><<<dim3(16, 64), 256, 0, stream>>>(Xh, WqR, Q, 2048, 2048, 2048, 2048);
  gemm_bt<_Float16><<<dim3(16, 64), 256, 0, stream>>>(Xh, WkR, Kh, 2048, 2048, 2048, 2048);

  // Vt_b[o][s] = sum_h Wv[o][h] * X_b[s][h]
  for (int b = 0; b < 2; ++b)
    gemm_bt<_Float16><<<dim3(32, 16), 256, 0, stream>>>(
        Wvh, Xh + (size_t)b * 4096 * 2048, Vt + (size_t)b * 2048 * 4096,
        2048, 2048, 2048, 4096);

  // S_b = Q_b · K_b^T   (scale already folded into Q)
  for (int b = 0; b < 2; ++b)
    gemm_bt<_Float16><<<dim3(32, 32), 256, 0, stream>>>(
        Q + (size_t)b * 4096 * 2048, Kh + (size_t)b * 4096 * 2048,
        Sm + (size_t)b * 4096 * 4096, 2048, 2048, 2048, 4096);

  softmax_rows<<<8192, 256, 0, stream>>>(Sm);

  // AO_b = P_b · Vt_b^T
  for (int b = 0; b < 2; ++b)
    gemm_bt<_Float16><<<dim3(16, 32), 256, 0, stream>>>(
        Sm + (size_t)b * 4096 * 4096, Vt + (size_t)b * 2048 * 4096,
        AO + (size_t)b * 4096 * 2048, 4096, 4096, 4096, 2048);

  // out = AO · Wo^T  (fp32 output)
  gemm_bt<float><<<dim3(16, 64), 256, 0, stream>>>(AO, Woh, out, 2048, 2048, 2048, 2048);
}

// Round 2
// 712.075 us; speedup vs baseline: 1.3224x; 1.3224x over previous
//
#include <hip/hip_runtime.h>
#include <hip/hip_fp16.h>

// ---------------------------------------------------------------------------
// CustomAttentionLayer: B=2, S=4096, H=2048. All matmuls as C = A·B^T via a
// 256x256-tile, 8-phase, counted-vmcnt fp16 MFMA GEMM (T2+T3+T4+T5 stack).
// ---------------------------------------------------------------------------

typedef _Float16 half8 __attribute__((ext_vector_type(8)));
typedef _Float16 half4v __attribute__((ext_vector_type(4)));
typedef float f32x4 __attribute__((ext_vector_type(4)));

using gas_t = const __attribute__((address_space(1))) void;
using las_t = __attribute__((address_space(3))) void;
#define GL2LDS16(g, l) __builtin_amdgcn_global_load_lds((gas_t*)(g), (las_t*)(l), 16, 0, 0)

#define BAR() __builtin_amdgcn_s_barrier()
#define VMW(N) asm volatile("s_waitcnt vmcnt(" #N ")" ::: "memory")

// LDS map (fp16 elems): buf b: A-region ks at b*32768 + ks*8192,
//                       B-region ks at b*32768 + 16384 + ks*8192.
// Region = 256 rows x 32 K-cols, row stride 32 elems (64B).
// Swizzle: 16B chunk c stored at c ^ ((row>>1)&3)  (2-way bank alias = free).

#define FRAGS(BUF, KS, QC)                                                        \
  half8 af[8], bf[2];                                                             \
  _Pragma("unroll") for (int mi = 0; mi < 8; ++mi)                                \
      af[mi] = *(const half8*)&lds[(BUF)*32768 + (KS)*8192 + aoff + mi*512];      \
  _Pragma("unroll") for (int ni = 0; ni < 2; ++ni)                                \
      bf[ni] = *(const half8*)&lds[(BUF)*32768 + 16384 + (KS)*8192 + boff + (QC)*1024 + ni*512];

#define MFMA8x2(QC)                                                               \
  __builtin_amdgcn_s_setprio(1);                                                  \
  _Pragma("unroll") for (int mi = 0; mi < 8; ++mi) {                              \
    acc[mi][(QC)*2+0] = __builtin_amdgcn_mfma_f32_16x16x32_f16(af[mi], bf[0], acc[mi][(QC)*2+0], 0, 0, 0); \
    acc[mi][(QC)*2+1] = __builtin_amdgcn_mfma_f32_16x16x32_f16(af[mi], bf[1], acc[mi][(QC)*2+1], 0, 0, 0); \
  }                                                                               \
  __builtin_amdgcn_s_setprio(0);

// Stage one (matrix, ks) region of K-tile at KT into buffer BUFI.
// Linear LDS dest + inverse-swizzled global source (rule #21).
#define STAGE(GP, LD, RB, KT, KS, BUFI, ISB)                                      \
  {                                                                               \
    const _Float16* _s = (GP) + (size_t)((RB) + srow) * (LD) + (KT) + (KS)*32 + scl*8; \
    _Float16* _d = lds + (BUFI)*32768 + (ISB)*16384 + (KS)*8192 + wv*512 + lane*8;     \
    GL2LDS16(_s, _d);                                                             \
    GL2LDS16(_s + (size_t)128*(LD), _d + 4096);                                   \
  }

template <typename OutT>
__global__ __launch_bounds__(512, 2) void gemm256(
    const _Float16* __restrict__ A, const _Float16* __restrict__ B,
    OutT* __restrict__ C, int K, int lda, int ldb, int ldc,
    size_t saz, size_t sbz, size_t scz) {
  extern __shared__ __align__(16) _Float16 lds[];

  const int tid = threadIdx.x;
  const int lane = tid & 63;
  const int wv = tid >> 6;
  const int wr = wv >> 2;                      // wave row 0..1 (128 rows each)
  const int wcol = wv & 3;                     // wave col 0..3 (64 cols each)
  const int r16 = lane & 15, kq = lane >> 4;
  const int chk = kq ^ ((r16 >> 1) & 3);       // swizzled 16B chunk for reads
  const int aoff = (wr * 128 + r16) * 32 + chk * 8;
  const int boff = (wcol * 64 + r16) * 32 + chk * 8;
  const int srow = (wv << 4) + (lane >> 2);    // staging row 0..127
  const int scl = (lane & 3) ^ ((lane >> 3) & 3);  // inverse-swizzled src chunk

  // bijective XCD swizzle over the whole grid (nwg % 8 == 0 for all launches)
  const int gx = gridDim.x, gy = gridDim.y;
  const int nwg = gx * gy * (int)gridDim.z;
  const int flat = blockIdx.x + gx * (blockIdx.y + gy * blockIdx.z);
  const int swz = (flat & 7) * (nwg >> 3) + (flat >> 3);
  const int tn = swz % gx;
  const int rem = swz / gx;
  const int tm = rem % gy;
  const int bz = rem / gy;
  const _Float16* Ab = A + (size_t)bz * saz;
  const _Float16* Bb = B + (size_t)bz * sbz;
  OutT* Cb = C + (size_t)bz * scz;
  const int mBase = tm * 256, nBase = tn * 256;

  f32x4 acc[8][4] = {};

  // Prologue: tile0 (all 4 regions) -> buf0, tile1 ks0 -> buf1.
  STAGE(Ab, lda, mBase, 0, 0, 0, 0);
  STAGE(Bb, ldb, nBase, 0, 0, 0, 1);
  STAGE(Ab, lda, mBase, 0, 1, 0, 0);
  STAGE(Bb, ldb, nBase, 0, 1, 0, 1);
  STAGE(Ab, lda, mBase, 64, 0, 1, 0);
  STAGE(Bb, ldb, nBase, 64, 0, 1, 1);
  VMW(4);  // tile0 fully landed (2 halves may remain in flight)
  BAR();

  const int NIT = K >> 7;  // iterations of 2 K-tiles (BK=64 each)
  for (int it = 0; it < NIT - 1; ++it) {
    const int kt1 = it * 128 + 64, kt2 = it * 128 + 128, kt3 = it * 128 + 192;
    { FRAGS(0,0,0); STAGE(Ab, lda, mBase, kt1, 1, 1, 0); BAR(); MFMA8x2(0); BAR(); }
    { FRAGS(0,0,1); STAGE(Bb, ldb, nBase, kt1, 1, 1, 1); BAR(); MFMA8x2(1); VMW(8); BAR(); }
    { FRAGS(0,1,0); STAGE(Ab, lda, mBase, kt2, 0, 0, 0); BAR(); MFMA8x2(0); BAR(); }
    { FRAGS(0,1,1); STAGE(Bb, ldb, nBase, kt2, 0, 0, 1); BAR(); MFMA8x2(1); VMW(8); BAR(); }
    { FRAGS(1,0,0); STAGE(Ab, lda, mBase, kt2, 1, 0, 0); BAR(); MFMA8x2(0); BAR(); }
    { FRAGS(1,0,1); STAGE(Bb, ldb, nBase, kt2, 1, 0, 1); BAR(); MFMA8x2(1); VMW(8); BAR(); }
    { FRAGS(1,1,0); STAGE(Ab, lda, mBase, kt3, 0, 1, 0); BAR(); MFMA8x2(0); BAR(); }
    { FRAGS(1,1,1); STAGE(Bb, ldb, nBase, kt3, 0, 1, 1); BAR(); MFMA8x2(1); VMW(8); BAR(); }
  }
  // Epilogue iteration (last 2 K-tiles): only tileNT-1 ks1 still to stage.
  const int ktL = K - 64;
  { FRAGS(0,0,0); STAGE(Ab, lda, mBase, ktL, 1, 1, 0); BAR(); MFMA8x2(0); BAR(); }
  { FRAGS(0,0,1); STAGE(Bb, ldb, nBase, ktL, 1, 1, 1); BAR(); MFMA8x2(1); VMW(8); BAR(); }
  { FRAGS(0,1,0); BAR(); MFMA8x2(0); BAR(); }
  { FRAGS(0,1,1); BAR(); MFMA8x2(1); VMW(4); BAR(); }
  { FRAGS(1,0,0); BAR(); MFMA8x2(0); BAR(); }
  { FRAGS(1,0,1); BAR(); MFMA8x2(1); VMW(0); BAR(); }
  { FRAGS(1,1,0); BAR(); MFMA8x2(0); BAR(); }
  { FRAGS(1,1,1); BAR(); MFMA8x2(1); }

  // C write. C/D layout: col = lane&15, row = kq*4 + reg (verified m89).
  const size_t crow0 = (size_t)mBase + wr * 128 + kq * 4;
  const size_t ccol = (size_t)nBase + wcol * 64 + r16;
#pragma unroll
  for (int mi = 0; mi < 8; ++mi)
#pragma unroll
    for (int n = 0; n < 4; ++n)
#pragma unroll
      for (int r = 0; r < 4; ++r)
        Cb[(crow0 + mi * 16 + r) * (size_t)ldc + ccol + n * 16] = (OutT)acc[mi][n][r];
}

// ---------------------------------------------------------------------------
// prep: z=0 rotate+scale wq, z=1 rotate wk, z=2/3 wv/wo->fp16, z=4 hidden->fp16
// ---------------------------------------------------------------------------
__global__ __launch_bounds__(256) void prep(
    const float* __restrict__ hid, const float* __restrict__ ang,
    const float* __restrict__ wq, const float* __restrict__ wk,
    const float* __restrict__ wv, const float* __restrict__ wo,
    _Float16* __restrict__ Xh, _Float16* __restrict__ WqR,
    _Float16* __restrict__ WkR, _Float16* __restrict__ Wvh,
    _Float16* __restrict__ Woh) {
  const int z = blockIdx.z;
  const int start = blockIdx.x * 256 + threadIdx.x;
  const int stride = gridDim.x * 256;
  if (z <= 1) {
    const float* w = z ? wk : wq;
    _Float16* o = z ? WkR : WqR;
    const float sc = z ? 1.0f : 0.08838834764831845f;  // 1/sqrt(128)
    for (int u = start; u < 1024 * 512; u += stride) {
      const int i = u >> 9;
      const int c = (u & 511) << 2;
      const float a = ang[i];
      const float cv = cosf(a) * sc, sv = sinf(a) * sc;
      f32x4 ar = *(const f32x4*)&w[(size_t)i * 2048 + c];
      f32x4 br = *(const f32x4*)&w[(size_t)(i + 1024) * 2048 + c];
      half4v r0, r1;
#pragma unroll
      for (int j = 0; j < 4; ++j) {
        r0[j] = (_Float16)(ar[j] * cv - br[j] * sv);
        r1[j] = (_Float16)(ar[j] * sv + br[j] * cv);
      }
      *(half4v*)&o[(size_t)(2 * i) * 2048 + c] = r0;
      *(half4v*)&o[(size_t)(2 * i + 1) * 2048 + c] = r1;
    }
  } else if (z <= 3) {
    const float* w = (z == 2) ? wv : wo;
    _Float16* o = (z == 2) ? Wvh : Woh;
    for (int u = start; u < 2048 * 512; u += stride) {
      const int c = u << 2;
      f32x4 a = *(const f32x4*)&w[c];
      half4v r;
#pragma unroll
      for (int j = 0; j < 4; ++j) r[j] = (_Float16)a[j];
      *(half4v*)&o[c] = r;
    }
  } else {
    for (int u = start; u < (2 * 4096 * 2048) / 4; u += stride) {
      const int c = u << 2;
      f32x4 a = *(const f32x4*)&hid[c];
      half4v r;
#pragma unroll
      for (int j = 0; j < 4; ++j) r[j] = (_Float16)a[j];
      *(half4v*)&Xh[c] = r;
    }
  }
}

// ---------------------------------------------------------------------------
// Row-wise softmax, in place, fp16 rows of length 4096. One block per row.
// ---------------------------------------------------------------------------
__global__ __launch_bounds__(256) void softmax_rows(_Float16* __restrict__ Sm) {
  _Float16* p = Sm + (size_t)blockIdx.x * 4096;
  const int tid = threadIdx.x;
  const int lane = tid & 63, wave = tid >> 6;
  __shared__ float red[8];

  half8 v0 = *(const half8*)&p[tid * 16];
  half8 v1 = *(const half8*)&p[tid * 16 + 8];
  float x[16];
#pragma unroll
  for (int j = 0; j < 8; ++j) { x[j] = (float)v0[j]; x[8 + j] = (float)v1[j]; }

  float m = x[0];
#pragma unroll
  for (int j = 1; j < 16; ++j) m = fmaxf(m, x[j]);
#pragma unroll
  for (int msk = 32; msk >= 1; msk >>= 1) m = fmaxf(m, __shfl_xor(m, msk));
  if (lane == 0) red[wave] = m;
  __syncthreads();
  m = fmaxf(fmaxf(red[0], red[1]), fmaxf(red[2], red[3]));

  float s = 0.f;
#pragma unroll
  for (int j = 0; j < 16; ++j) { x[j] = __expf(x[j] - m); s += x[j]; }
#pragma unroll
  for (int msk = 32; msk >= 1; msk >>= 1) s += __shfl_xor(s, msk);
  if (lane == 0) red[4 + wave] = s;
  __syncthreads();
  s = red[4] + red[5] + red[6] + red[7];
  const float inv = 1.0f / s;

#pragma unroll
  for (int j = 0; j < 8; ++j) {
    v0[j] = (_Float16)(x[j] * inv);
    v1[j] = (_Float16)(x[8 + j] * inv);
  }
  *(half8*)&p[tid * 16] = v0;
  *(half8*)&p[tid * 16 + 8] = v1;
}

// ---------------------------------------------------------------------------
extern "C" void kernel_launch(void* const* d_in, const int* in_sizes, int n_in,
                              void* d_out, int out_size, void* d_ws, size_t ws_size,
                              hipStream_t stream) {
  (void)in_sizes; (void)n_in; (void)out_size; (void)ws_size;
  const float* hid = (const float*)d_in[0];
  const float* ang = (const float*)d_in[1];
  const float* wq  = (const float*)d_in[2];
  const float* wk  = (const float*)d_in[3];
  const float* wv  = (const float*)d_in[4];
  const float* wo  = (const float*)d_in[5];
  float* out = (float*)d_out;

  _Float16* ws = (_Float16*)d_ws;
  const size_t EX = 2ull * 4096 * 2048;  // 16777216 elems
  const size_t EH = 2048ull * 2048;      // 4194304 elems
  _Float16* Xh  = ws;                 // [8192][2048]
  _Float16* AO  = ws;                 // alias: Xh dead after Vt projections
  _Float16* Q   = ws + EX;            // [8192][2048] (Q then Kh contiguous)
  _Float16* Kh  = ws + 2 * EX;
  _Float16* Vt  = ws + 3 * EX;        // per batch [2048][4096]
  _Float16* WqR = ws + 4 * EX;        // WqR,WkR contiguous for z-stride
  _Float16* WkR = WqR + EH;
  _Float16* Wvh = WkR + EH;
  _Float16* Woh = Wvh + EH;
  _Float16* Sm  = Woh + EH;           // [2][4096][4096]

  (void)hipFuncSetAttribute((const void*)&gemm256<_Float16>,
                            hipFuncAttributeMaxDynamicSharedMemorySize, 131072);
  (void)hipFuncSetAttribute((const void*)&gemm256<float>,
                            hipFuncAttributeMaxDynamicSharedMemorySize, 131072);

  prep<<<dim3(2048, 1, 5), 256, 0, stream>>>(hid, ang, wq, wk, wv, wo, Xh, WqR, WkR, Wvh, Woh);

  // Q and K projections fused over z (B: WqR->WkR stride EH; C: Q->Kh stride EX)
  gemm256<_Float16><<<dim3(8, 32, 2), 512, 131072, stream>>>(
      Xh, WqR, Q, 2048, 2048, 2048, 2048, 0, EH, EX);

  // Vt_b = Wvh · Xh_b^T  (both batches in one launch)
  gemm256<_Float16><<<dim3(16, 8, 2), 512, 131072, stream>>>(
      Wvh, Xh, Vt, 2048, 2048, 2048, 4096, 0, (size_t)4096 * 2048, (size_t)2048 * 4096);

  // S_b = Q_b · K_b^T (scale folded into Q)
  gemm256<_Float16><<<dim3(16, 16, 2), 512, 131072, stream>>>(
      Q, Kh, Sm, 2048, 2048, 2048, 4096, (size_t)4096 * 2048, (size_t)4096 * 2048,
      (size_t)4096 * 4096);

  softmax_rows<<<8192, 256, 0, stream>>>(Sm);

  // AO_b = P_b · Vt_b^T
  gemm256<_Float16><<<dim3(8, 16, 2), 512, 131072, stream>>>(
      Sm, Vt, AO, 4096, 4096, 4096, 2048, (size_t)4096 * 4096, (size_t)2048 * 4096,
      (size_t)4096 * 2048);

  // out = AO · Wo^T (fp32 output)
  gemm256<float><<<dim3(8, 32, 1), 512, 131072, stream>>>(
      AO, Woh, out, 2048, 2048, 2048, 2048, 0, 0, 0);
}

// Round 3
// 674.176 us; speedup vs baseline: 1.3967x; 1.0562x over previous
//
#include <hip/hip_runtime.h>
#include <hip/hip_fp16.h>

// ---------------------------------------------------------------------------
// CustomAttentionLayer: B=2, S=4096, H=2048. All matmuls as C = A·B^T via a
// 256x256-tile, 8-phase, counted-vmcnt fp16 MFMA GEMM (T2+T3+T4+T5 stack).
// R3: A-fragments loaded once per (buf,ks) and held in regs across the two
//     QC phases (LDS reads/iter 80 -> 48; LDS BW was the limiter).
// ---------------------------------------------------------------------------

typedef _Float16 half8 __attribute__((ext_vector_type(8)));
typedef _Float16 half4v __attribute__((ext_vector_type(4)));
typedef float f32x4 __attribute__((ext_vector_type(4)));

using gas_t = const __attribute__((address_space(1))) void;
using las_t = __attribute__((address_space(3))) void;
#define GL2LDS16(g, l) __builtin_amdgcn_global_load_lds((gas_t*)(g), (las_t*)(l), 16, 0, 0)

#define BAR() __builtin_amdgcn_s_barrier()
#define VMW(N) asm volatile("s_waitcnt vmcnt(" #N ")" ::: "memory")

// LDS map (fp16 elems): buf b: A-region ks at b*32768 + ks*8192,
//                       B-region ks at b*32768 + 16384 + ks*8192.
// Region = 256 rows x 32 K-cols, row stride 32 elems (64B).
// Swizzle: 16B chunk c stored at c ^ ((row>>1)&3)  (2-way bank alias = free).

#define LDA8(BUF, KS)                                                             \
  _Pragma("unroll") for (int mi = 0; mi < 8; ++mi)                                \
      af[mi] = *(const half8*)&lds[(BUF)*32768 + (KS)*8192 + aoff + mi*512];

#define LDB2(BUF, KS, QC)                                                         \
  _Pragma("unroll") for (int ni = 0; ni < 2; ++ni)                                \
      bf[ni] = *(const half8*)&lds[(BUF)*32768 + 16384 + (KS)*8192 + boff + (QC)*1024 + ni*512];

#define MFMA8x2(QC)                                                               \
  __builtin_amdgcn_s_setprio(1);                                                  \
  _Pragma("unroll") for (int mi = 0; mi < 8; ++mi) {                              \
    acc[mi][(QC)*2+0] = __builtin_amdgcn_mfma_f32_16x16x32_f16(af[mi], bf[0], acc[mi][(QC)*2+0], 0, 0, 0); \
    acc[mi][(QC)*2+1] = __builtin_amdgcn_mfma_f32_16x16x32_f16(af[mi], bf[1], acc[mi][(QC)*2+1], 0, 0, 0); \
  }                                                                               \
  __builtin_amdgcn_s_setprio(0);

// Stage one (matrix, ks) region of K-tile at KT into buffer BUFI.
// Linear LDS dest + inverse-swizzled global source (rule #21).
#define STAGE(GP, LD, RB, KT, KS, BUFI, ISB)                                      \
  {                                                                               \
    const _Float16* _s = (GP) + (size_t)((RB) + srow) * (LD) + (KT) + (KS)*32 + scl*8; \
    _Float16* _d = lds + (BUFI)*32768 + (ISB)*16384 + (KS)*8192 + wv*512 + lane*8;     \
    GL2LDS16(_s, _d);                                                             \
    GL2LDS16(_s + (size_t)128*(LD), _d + 4096);                                   \
  }

template <typename OutT>
__global__ __launch_bounds__(512, 2) void gemm256(
    const _Float16* __restrict__ A, const _Float16* __restrict__ B,
    OutT* __restrict__ C, int K, int lda, int ldb, int ldc,
    size_t saz, size_t sbz, size_t scz) {
  extern __shared__ __align__(16) _Float16 lds[];

  const int tid = threadIdx.x;
  const int lane = tid & 63;
  const int wv = tid >> 6;
  const int wr = wv >> 2;                      // wave row 0..1 (128 rows each)
  const int wcol = wv & 3;                     // wave col 0..3 (64 cols each)
  const int r16 = lane & 15, kq = lane >> 4;
  const int chk = kq ^ ((r16 >> 1) & 3);       // swizzled 16B chunk for reads
  const int aoff = (wr * 128 + r16) * 32 + chk * 8;
  const int boff = (wcol * 64 + r16) * 32 + chk * 8;
  const int srow = (wv << 4) + (lane >> 2);    // staging row 0..127
  const int scl = (lane & 3) ^ ((lane >> 3) & 3);  // inverse-swizzled src chunk

  // bijective XCD swizzle over the whole grid (nwg % 8 == 0 for all launches)
  const int gx = gridDim.x, gy = gridDim.y;
  const int nwg = gx * gy * (int)gridDim.z;
  const int flat = blockIdx.x + gx * (blockIdx.y + gy * blockIdx.z);
  const int swz = (flat & 7) * (nwg >> 3) + (flat >> 3);
  const int tn = swz % gx;
  const int rem = swz / gx;
  const int tm = rem % gy;
  const int bz = rem / gy;
  const _Float16* Ab = A + (size_t)bz * saz;
  const _Float16* Bb = B + (size_t)bz * sbz;
  OutT* Cb = C + (size_t)bz * scz;
  const int mBase = tm * 256, nBase = tn * 256;

  f32x4 acc[8][4] = {};
  half8 af[8], bf[2];

  // Prologue: tile0 (all 4 regions) -> buf0, tile1 ks0 -> buf1.
  STAGE(Ab, lda, mBase, 0, 0, 0, 0);
  STAGE(Bb, ldb, nBase, 0, 0, 0, 1);
  STAGE(Ab, lda, mBase, 0, 1, 0, 0);
  STAGE(Bb, ldb, nBase, 0, 1, 0, 1);
  STAGE(Ab, lda, mBase, 64, 0, 1, 0);
  STAGE(Bb, ldb, nBase, 64, 0, 1, 1);
  VMW(4);  // tile0 fully landed (2 halves may remain in flight)
  BAR();

  const int NIT = K >> 7;  // iterations of 2 K-tiles (BK=64 each)
  for (int it = 0; it < NIT - 1; ++it) {
    const int kt1 = it * 128 + 64, kt2 = it * 128 + 128, kt3 = it * 128 + 192;
    { LDA8(0,0); LDB2(0,0,0); STAGE(Ab, lda, mBase, kt1, 1, 1, 0); BAR(); MFMA8x2(0); BAR(); }
    { LDB2(0,0,1);            STAGE(Bb, ldb, nBase, kt1, 1, 1, 1); BAR(); MFMA8x2(1); VMW(8); BAR(); }
    { LDA8(0,1); LDB2(0,1,0); STAGE(Ab, lda, mBase, kt2, 0, 0, 0); BAR(); MFMA8x2(0); BAR(); }
    { LDB2(0,1,1);            STAGE(Bb, ldb, nBase, kt2, 0, 0, 1); BAR(); MFMA8x2(1); VMW(8); BAR(); }
    { LDA8(1,0); LDB2(1,0,0); STAGE(Ab, lda, mBase, kt2, 1, 0, 0); BAR(); MFMA8x2(0); BAR(); }
    { LDB2(1,0,1);            STAGE(Bb, ldb, nBase, kt2, 1, 0, 1); BAR(); MFMA8x2(1); VMW(8); BAR(); }
    { LDA8(1,1); LDB2(1,1,0); STAGE(Ab, lda, mBase, kt3, 0, 1, 0); BAR(); MFMA8x2(0); BAR(); }
    { LDB2(1,1,1);            STAGE(Bb, ldb, nBase, kt3, 0, 1, 1); BAR(); MFMA8x2(1); VMW(8); BAR(); }
  }
  // Epilogue iteration (last 2 K-tiles): only tileNT-1 ks1 still to stage.
  const int ktL = K - 64;
  { LDA8(0,0); LDB2(0,0,0); STAGE(Ab, lda, mBase, ktL, 1, 1, 0); BAR(); MFMA8x2(0); BAR(); }
  { LDB2(0,0,1);            STAGE(Bb, ldb, nBase, ktL, 1, 1, 1); BAR(); MFMA8x2(1); VMW(8); BAR(); }
  { LDA8(0,1); LDB2(0,1,0); BAR(); MFMA8x2(0); BAR(); }
  { LDB2(0,1,1);            BAR(); MFMA8x2(1); VMW(4); BAR(); }
  { LDA8(1,0); LDB2(1,0,0); BAR(); MFMA8x2(0); BAR(); }
  { LDB2(1,0,1);            BAR(); MFMA8x2(1); VMW(0); BAR(); }
  { LDA8(1,1); LDB2(1,1,0); BAR(); MFMA8x2(0); BAR(); }
  { LDB2(1,1,1);            BAR(); MFMA8x2(1); }

  // C write. C/D layout: col = lane&15, row = kq*4 + reg (verified m89).
  const size_t crow0 = (size_t)mBase + wr * 128 + kq * 4;
  const size_t ccol = (size_t)nBase + wcol * 64 + r16;
#pragma unroll
  for (int mi = 0; mi < 8; ++mi)
#pragma unroll
    for (int n = 0; n < 4; ++n)
#pragma unroll
      for (int r = 0; r < 4; ++r)
        Cb[(crow0 + mi * 16 + r) * (size_t)ldc + ccol + n * 16] = (OutT)acc[mi][n][r];
}

// ---------------------------------------------------------------------------
// prep: z=0 rotate+scale wq, z=1 rotate wk, z=2/3 wv/wo->fp16, z=4 hidden->fp16
// ---------------------------------------------------------------------------
__global__ __launch_bounds__(256) void prep(
    const float* __restrict__ hid, const float* __restrict__ ang,
    const float* __restrict__ wq, const float* __restrict__ wk,
    const float* __restrict__ wv, const float* __restrict__ wo,
    _Float16* __restrict__ Xh, _Float16* __restrict__ WqR,
    _Float16* __restrict__ WkR, _Float16* __restrict__ Wvh,
    _Float16* __restrict__ Woh) {
  const int z = blockIdx.z;
  const int start = blockIdx.x * 256 + threadIdx.x;
  const int stride = gridDim.x * 256;
  if (z <= 1) {
    const float* w = z ? wk : wq;
    _Float16* o = z ? WkR : WqR;
    const float sc = z ? 1.0f : 0.08838834764831845f;  // 1/sqrt(128)
    for (int u = start; u < 1024 * 512; u += stride) {
      const int i = u >> 9;
      const int c = (u & 511) << 2;
      const float a = ang[i];
      const float cv = cosf(a) * sc, sv = sinf(a) * sc;
      f32x4 ar = *(const f32x4*)&w[(size_t)i * 2048 + c];
      f32x4 br = *(const f32x4*)&w[(size_t)(i + 1024) * 2048 + c];
      half4v r0, r1;
#pragma unroll
      for (int j = 0; j < 4; ++j) {
        r0[j] = (_Float16)(ar[j] * cv - br[j] * sv);
        r1[j] = (_Float16)(ar[j] * sv + br[j] * cv);
      }
      *(half4v*)&o[(size_t)(2 * i) * 2048 + c] = r0;
      *(half4v*)&o[(size_t)(2 * i + 1) * 2048 + c] = r1;
    }
  } else if (z <= 3) {
    const float* w = (z == 2) ? wv : wo;
    _Float16* o = (z == 2) ? Wvh : Woh;
    for (int u = start; u < 2048 * 512; u += stride) {
      const int c = u << 2;
      f32x4 a = *(const f32x4*)&w[c];
      half4v r;
#pragma unroll
      for (int j = 0; j < 4; ++j) r[j] = (_Float16)a[j];
      *(half4v*)&o[c] = r;
    }
  } else {
    for (int u = start; u < (2 * 4096 * 2048) / 4; u += stride) {
      const int c = u << 2;
      f32x4 a = *(const f32x4*)&hid[c];
      half4v r;
#pragma unroll
      for (int j = 0; j < 4; ++j) r[j] = (_Float16)a[j];
      *(half4v*)&Xh[c] = r;
    }
  }
}

// ---------------------------------------------------------------------------
// Row-wise softmax, in place, fp16 rows of length 4096. One block per row.
// ---------------------------------------------------------------------------
__global__ __launch_bounds__(256) void softmax_rows(_Float16* __restrict__ Sm) {
  _Float16* p = Sm + (size_t)blockIdx.x * 4096;
  const int tid = threadIdx.x;
  const int lane = tid & 63, wave = tid >> 6;
  __shared__ float red[8];

  half8 v0 = *(const half8*)&p[tid * 16];
  half8 v1 = *(const half8*)&p[tid * 16 + 8];
  float x[16];
#pragma unroll
  for (int j = 0; j < 8; ++j) { x[j] = (float)v0[j]; x[8 + j] = (float)v1[j]; }

  float m = x[0];
#pragma unroll
  for (int j = 1; j < 16; ++j) m = fmaxf(m, x[j]);
#pragma unroll
  for (int msk = 32; msk >= 1; msk >>= 1) m = fmaxf(m, __shfl_xor(m, msk));
  if (lane == 0) red[wave] = m;
  __syncthreads();
  m = fmaxf(fmaxf(red[0], red[1]), fmaxf(red[2], red[3]));

  float s = 0.f;
#pragma unroll
  for (int j = 0; j < 16; ++j) { x[j] = __expf(x[j] - m); s += x[j]; }
#pragma unroll
  for (int msk = 32; msk >= 1; msk >>= 1) s += __shfl_xor(s, msk);
  if (lane == 0) red[4 + wave] = s;
  __syncthreads();
  s = red[4] + red[5] + red[6] + red[7];
  const float inv = 1.0f / s;

#pragma unroll
  for (int j = 0; j < 8; ++j) {
    v0[j] = (_Float16)(x[j] * inv);
    v1[j] = (_Float16)(x[8 + j] * inv);
  }
  *(half8*)&p[tid * 16] = v0;
  *(half8*)&p[tid * 16 + 8] = v1;
}

// ---------------------------------------------------------------------------
extern "C" void kernel_launch(void* const* d_in, const int* in_sizes, int n_in,
                              void* d_out, int out_size, void* d_ws, size_t ws_size,
                              hipStream_t stream) {
  (void)in_sizes; (void)n_in; (void)out_size; (void)ws_size;
  const float* hid = (const float*)d_in[0];
  const float* ang = (const float*)d_in[1];
  const float* wq  = (const float*)d_in[2];
  const float* wk  = (const float*)d_in[3];
  const float* wv  = (const float*)d_in[4];
  const float* wo  = (const float*)d_in[5];
  float* out = (float*)d_out;

  _Float16* ws = (_Float16*)d_ws;
  const size_t EX = 2ull * 4096 * 2048;  // 16777216 elems
  const size_t EH = 2048ull * 2048;      // 4194304 elems
  _Float16* Xh  = ws;                 // [8192][2048]
  _Float16* AO  = ws;                 // alias: Xh dead after Vt projections
  _Float16* Q   = ws + EX;            // [8192][2048] (Q then Kh contiguous)
  _Float16* Kh  = ws + 2 * EX;
  _Float16* Vt  = ws + 3 * EX;        // per batch [2048][4096]
  _Float16* WqR = ws + 4 * EX;        // WqR,WkR contiguous for z-stride
  _Float16* WkR = WqR + EH;
  _Float16* Wvh = WkR + EH;
  _Float16* Woh = Wvh + EH;
  _Float16* Sm  = Woh + EH;           // [2][4096][4096]

  (void)hipFuncSetAttribute((const void*)&gemm256<_Float16>,
                            hipFuncAttributeMaxDynamicSharedMemorySize, 131072);
  (void)hipFuncSetAttribute((const void*)&gemm256<float>,
                            hipFuncAttributeMaxDynamicSharedMemorySize, 131072);

  prep<<<dim3(2048, 1, 5), 256, 0, stream>>>(hid, ang, wq, wk, wv, wo, Xh, WqR, WkR, Wvh, Woh);

  // Q and K projections fused over z (B: WqR->WkR stride EH; C: Q->Kh stride EX)
  gemm256<_Float16><<<dim3(8, 32, 2), 512, 131072, stream>>>(
      Xh, WqR, Q, 2048, 2048, 2048, 2048, 0, EH, EX);

  // Vt_b = Wvh · Xh_b^T  (both batches in one launch)
  gemm256<_Float16><<<dim3(16, 8, 2), 512, 131072, stream>>>(
      Wvh, Xh, Vt, 2048, 2048, 2048, 4096, 0, (size_t)4096 * 2048, (size_t)2048 * 4096);

  // S_b = Q_b · K_b^T (scale folded into Q)
  gemm256<_Float16><<<dim3(16, 16, 2), 512, 131072, stream>>>(
      Q, Kh, Sm, 2048, 2048, 2048, 4096, (size_t)4096 * 2048, (size_t)4096 * 2048,
      (size_t)4096 * 4096);

  softmax_rows<<<8192, 256, 0, stream>>>(Sm);

  // AO_b = P_b · Vt_b^T
  gemm256<_Float16><<<dim3(8, 16, 2), 512, 131072, stream>>>(
      Sm, Vt, AO, 4096, 4096, 4096, 2048, (size_t)4096 * 4096, (size_t)2048 * 4096,
      (size_t)4096 * 2048);

  // out = AO · Wo^T (fp32 output)
  gemm256<float><<<dim3(8, 32, 1), 512, 131072, stream>>>(
      AO, Woh, out, 2048, 2048, 2048, 2048, 0, 0, 0);
}